// Round 6
// baseline (220.906 us; speedup 1.0000x reference)
//
#include <hip/hip_runtime.h>

typedef __attribute__((ext_vector_type(8))) short s8bf;    // 8 x bf16
typedef __attribute__((ext_vector_type(4))) float f4;
typedef __attribute__((ext_vector_type(2))) unsigned u2;
typedef __attribute__((ext_vector_type(4))) unsigned u4;

#define HQ 32
#define HK 8
#define DH 128

// single-instruction pack of 2 f32 -> 2 bf16 (RNE); no builtin on gfx950
static __device__ __forceinline__ unsigned cvtpk(float a, float b) {
  unsigned r;
  asm("v_cvt_pk_bf16_f32 %0, %1, %2" : "=v"(r) : "v"(a), "v"(b));
  return r;
}
union frag_u { s8bf v; unsigned u[4]; };

// async global->LDS, 16B per lane; LDS dest is wave-uniform base + lane*16.
static __device__ __forceinline__ void gload_lds16(const short* g, short* l) {
  __builtin_amdgcn_global_load_lds(
      (const __attribute__((address_space(1))) void*)g,
      (__attribute__((address_space(3))) void*)l, 16, 0, 0);
}

// Counted wait + scheduler fence (rule #18).
#define WAIT_VM(N)                                         \
  do {                                                     \
    asm volatile("s_waitcnt vmcnt(" #N ")" ::: "memory");  \
    __builtin_amdgcn_sched_barrier(0);                     \
  } while (0)

// K stored in LOGICAL key order. V stored with the key interleave that makes
// the S^T accumulator registers directly the PV B-fragment.

// ---------------- prepass ----------------
// blocks 0..511  : K -> bf16 frag-major [bg][kt64][f=ct*4+dk][lane]
// blocks 512..1023: V half-tiles (32 keys) -> frag-major via LDS transpose
__global__ void prep_kernel(const float* __restrict__ kg, const float* __restrict__ vg,
                            short* __restrict__ kbt, short* __restrict__ vbt) {
  const int blk = blockIdx.x;
  if (blk < 512) {
    const int gid = blk * 256 + threadIdx.x;
#pragma unroll
    for (int i = 0; i < 2; ++i) {
      int c = gid + i * 131072;
      int l16 = c & 15, quad = (c >> 4) & 3;
      int f = (c >> 6) & 15;
      int kt = (c >> 10) & 15;
      int bg = c >> 14;
      int b = bg >> 3, g = bg & 7;
      int key = kt * 64 + (f >> 2) * 16 + l16;
      int d0 = (f & 3) * 32 + quad * 8;
      const float* src = kg + (((size_t)(b * 1024 + key) * HK + g) * DH + d0);
      f4 a = *(const f4*)src, cc = *(const f4*)(src + 4);
      u4 w;
      w[0] = cvtpk(a[0], a[1]);   w[1] = cvtpk(a[2], a[3]);
      w[2] = cvtpk(cc[0], cc[1]); w[3] = cvtpk(cc[2], cc[3]);
      *(u4*)(kbt + (size_t)c * 8) = w;
    }
  } else {
    // V: one (bg,kt,half) 32x128 half-tile per block
    __shared__ short T[32 * 130];
    const int t = blk - 512;               // 0..511
    const int half = t & 1, tile = t >> 1; // half = ks
    const int bg = tile >> 4, kt = tile & 15;
    const int b = bg >> 3, g = bg & 7;
#pragma unroll
    for (int i = 0; i < 4; ++i) {
      int e = threadIdx.x * 4 + i * 1024;  // 32 key x 128 d
      int key = e >> 7, d = e & 127;
      f4 x = *(const f4*)(vg + (((size_t)(b * 1024 + kt * 64 + half * 32 + key) * HK + g) * DH + d));
      u2 w; w[0] = cvtpk(x[0], x[1]); w[1] = cvtpk(x[2], x[3]);
      *(u2*)&T[key * 130 + d] = w;
    }
    __syncthreads();
    short* dst = vbt + (size_t)(bg * 16 + kt) * 8192;
#pragma unroll
    for (int i = 0; i < 2; ++i) {
      int c = threadIdx.x + i * 256;       // 512 cells: frags f = dt*2+half
      int lane = c & 63, dt = c >> 6;
      int fidx = dt * 2 + half;
      int l16 = lane & 15, quad = (lane >> 4) & 3;
      int d = dt * 16 + l16;
      int k0 = quad * 4;                   // local keys for j=0..3
      int k1 = k0 + 16;                    // local keys for j=4..7
      u4 w;
      w[0] = (unsigned)(unsigned short)T[(k0 + 0) * 130 + d] |
             ((unsigned)(unsigned short)T[(k0 + 1) * 130 + d] << 16);
      w[1] = (unsigned)(unsigned short)T[(k0 + 2) * 130 + d] |
             ((unsigned)(unsigned short)T[(k0 + 3) * 130 + d] << 16);
      w[2] = (unsigned)(unsigned short)T[(k1 + 0) * 130 + d] |
             ((unsigned)(unsigned short)T[(k1 + 1) * 130 + d] << 16);
      w[3] = (unsigned)(unsigned short)T[(k1 + 2) * 130 + d] |
             ((unsigned)(unsigned short)T[(k1 + 3) * 130 + d] << 16);
      *(u4*)(dst + (size_t)(fidx * 64 + lane) * 8) = w;
    }
  }
}

// ---------------- main: 32-key tiles, 32KB LDS -> 4 blocks/CU (16 waves/CU) ----------------
// Block covers q-tiles (2pt, 2pt+1); all 512 blocks co-resident; A skipped when dead.
__launch_bounds__(256, 4)
__global__ void fa_main(const float* __restrict__ qg, const short* __restrict__ kbt,
                        const short* __restrict__ vbt, float* __restrict__ out) {
  const int id  = blockIdx.x;            // 0..511; id&7 -> XCD-aligned kv-head
  const int g   = id & 7;
  const int s   = id >> 3;               // 0..63
  const int pt  = s >> 3;                // q-tile pair 0..7
  const int rem = s & 7;
  const int b   = rem >> 2;
  const int h   = g * 4 + (rem & 3);
  const int bg  = b * 8 + g;
  const int qtA = 2 * pt, qtB = 2 * pt + 1;
  const int kAmax = 4 * pt + 1;          // last 32-key tile where A is live
  const int kBmax = 4 * pt + 3;          // loop bound (B diagonal)

  const int tid  = threadIdx.x;
  const int wave = tid >> 6, lane = tid & 63;
  const int l16  = lane & 15, quad = lane >> 4;
  const int qlocal = wave * 16 + l16;    // row within a 64-row q-tile
  const int seq0 = b * 1024;

  // [buf][ K frags: 0..4095 shorts | V frags: 4096..8191 ]  = 32 KB total
  __shared__ short smem[2][8192];

  // ---- Q fragments for both tiles, softmax scale folded in (exp2 domain)
  const float qmul = 0.08838834764831845f * 1.4426950408889634f;
  const float* qpA = qg + ((size_t)(seq0 + qtA * 64 + qlocal) * HQ + h) * DH;
  const float* qpB = qg + ((size_t)(seq0 + qtB * 64 + qlocal) * HQ + h) * DH;
  s8bf qfA[4], qfB[4];
#pragma unroll
  for (int dk = 0; dk < 4; ++dk) {
    const float* pA = qpA + dk * 32 + quad * 8;
    const float* pB = qpB + dk * 32 + quad * 8;
    f4 a0 = *(const f4*)pA, a1 = *(const f4*)(pA + 4);
    f4 b0 = *(const f4*)pB, b1 = *(const f4*)(pB + 4);
    frag_u ta, tb;
    ta.u[0] = cvtpk(a0[0] * qmul, a0[1] * qmul);
    ta.u[1] = cvtpk(a0[2] * qmul, a0[3] * qmul);
    ta.u[2] = cvtpk(a1[0] * qmul, a1[1] * qmul);
    ta.u[3] = cvtpk(a1[2] * qmul, a1[3] * qmul);
    tb.u[0] = cvtpk(b0[0] * qmul, b0[1] * qmul);
    tb.u[1] = cvtpk(b0[2] * qmul, b0[3] * qmul);
    tb.u[2] = cvtpk(b1[0] * qmul, b1[1] * qmul);
    tb.u[3] = cvtpk(b1[2] * qmul, b1[3] * qmul);
    qfA[dk] = ta.v;
    qfB[dk] = tb.v;
  }

  float lA = 0.0f, lB = 0.0f;            // per-lane partial denoms
  f4 oaccA[8], oaccB[8];
#pragma unroll
  for (int dt = 0; dt < 8; ++dt) { oaccA[dt] = (f4)(0.0f); oaccB[dt] = (f4)(0.0f); }

  // K 32-tile j lives at kbt + (bg*16 + (j>>1))*8192 + (j&1)*4096 (contiguous 8 frags).
  // V 32-tile j: frags f = dt*2 + (j&1) within vbt tile (j>>1) (strided 1KB).
  const short* ktile = kbt + (size_t)bg * 16 * 8192;
  const short* vtile = vbt + (size_t)bg * 16 * 8192;

  // ---- pin Q loads above the counted-vmcnt stream
  __builtin_amdgcn_sched_barrier(0);

  // ---- staging helper pattern: 16 frags (8 K + 8 V), 4 per wave
#define STAGE_TILE(J, BUF)                                                             \
  do {                                                                                 \
    const short* kb32 = ktile + (size_t)((J) >> 1) * 8192 + ((J) & 1) * 4096;          \
    const short* vb32 = vtile + (size_t)((J) >> 1) * 8192 + ((J) & 1) * 512;           \
    _Pragma("unroll")                                                                  \
    for (int i = 0; i < 4; ++i) {                                                      \
      int fidx = wave * 4 + i;                                                         \
      if (fidx < 8) {                                                                  \
        gload_lds16(kb32 + (size_t)(fidx * 64 + lane) * 8, &smem[BUF][fidx * 512]);    \
      } else {                                                                         \
        gload_lds16(vb32 + (size_t)((fidx - 8) * 128 + lane) * 8,                      \
                    &smem[BUF][4096 + (fidx - 8) * 512]);                              \
      }                                                                                \
    }                                                                                  \
  } while (0)

  // ---- preloop: stage tile 0 into buf 0
  STAGE_TILE(0, 0);

  for (int kt = 0; kt <= kBmax; ++kt) {
    const int cur = kt & 1;
    const bool aAct = (kt <= kAmax);     // wave-uniform

    if (kt < kBmax) {
      STAGE_TILE(kt + 1, cur ^ 1);
      WAIT_VM(4);     // own tile-kt loads (older 4) landed; kt+1 stays in flight
    } else {
      WAIT_VM(0);     // last iteration: drain everything
    }
    __builtin_amdgcn_s_barrier();        // all waves' tile-kt loads landed
    __builtin_amdgcn_sched_barrier(0);

    const short* kb = &smem[cur][lane * 8];
    const short* vb = &smem[cur][4096 + lane * 8];

    // ---- S^T = K Q^T (2 key-subtiles x 4 dk); each kf feeds A and B
    f4 saccA[2], saccB[2];
#pragma unroll
    for (int ct = 0; ct < 2; ++ct) { saccA[ct] = (f4)(0.0f); saccB[ct] = (f4)(0.0f); }
    __builtin_amdgcn_s_setprio(1);
#pragma unroll
    for (int dk = 0; dk < 4; ++dk)
#pragma unroll
      for (int ct = 0; ct < 2; ++ct) {
        s8bf kf = *(const s8bf*)&kb[(ct * 4 + dk) * 512];
        if (aAct)
          saccA[ct] = __builtin_amdgcn_mfma_f32_16x16x32_bf16(kf, qfA[dk], saccA[ct], 0, 0, 0);
        saccB[ct] = __builtin_amdgcn_mfma_f32_16x16x32_bf16(kf, qfB[dk], saccB[ct], 0, 0, 0);
      }
    __builtin_amdgcn_s_setprio(0);

    // ---- causal masks: key_local > qlocal - (kt - diag0)*32 -> -inf
    if (aAct && kt >= 4 * pt) {
      int thrA = qlocal - (kt - 4 * pt) * 32;
#pragma unroll
      for (int ct = 0; ct < 2; ++ct)
#pragma unroll
        for (int i = 0; i < 4; ++i) {
          int key = ct * 16 + quad * 4 + i;
          if (key > thrA) saccA[ct][i] = -1e30f;
        }
    }
    if (kt >= 4 * pt + 2) {
      int thrB = qlocal - (kt - 4 * pt - 2) * 32;
#pragma unroll
      for (int ct = 0; ct < 2; ++ct)
#pragma unroll
        for (int i = 0; i < 4; ++i) {
          int key = ct * 16 + quad * 4 + i;
          if (key > thrB) saccB[ct][i] = -1e30f;
        }
    }

    // ---- static-max softmax: p = exp2(min(s,30)); normalization in epilogue
    frag_u frA, frB;
    if (aAct) {
      float rsA = 0.0f;
#pragma unroll
      for (int ct = 0; ct < 2; ++ct) {
        float a0 = exp2f(fminf(saccA[ct][0], 30.0f));
        float a1 = exp2f(fminf(saccA[ct][1], 30.0f));
        float a2 = exp2f(fminf(saccA[ct][2], 30.0f));
        float a3 = exp2f(fminf(saccA[ct][3], 30.0f));
        rsA += (a0 + a1) + (a2 + a3);
        frA.u[ct * 2 + 0] = cvtpk(a0, a1);
        frA.u[ct * 2 + 1] = cvtpk(a2, a3);
      }
      lA += rsA;
    }
    {
      float rsB = 0.0f;
#pragma unroll
      for (int ct = 0; ct < 2; ++ct) {
        float b0 = exp2f(fminf(saccB[ct][0], 30.0f));
        float b1 = exp2f(fminf(saccB[ct][1], 30.0f));
        float b2 = exp2f(fminf(saccB[ct][2], 30.0f));
        float b3 = exp2f(fminf(saccB[ct][3], 30.0f));
        rsB += (b0 + b1) + (b2 + b3);
        frB.u[ct * 2 + 0] = cvtpk(b0, b1);
        frB.u[ct * 2 + 1] = cvtpk(b2, b3);
      }
      lB += rsB;
    }

    // ---- O^T += V^T P^T : P fragment is a register rename of the packed exp2s
    __builtin_amdgcn_s_setprio(1);
#pragma unroll
    for (int dt = 0; dt < 8; ++dt) {
      s8bf vf = *(const s8bf*)&vb[dt * 512];
      if (aAct)
        oaccA[dt] = __builtin_amdgcn_mfma_f32_16x16x32_bf16(vf, frA.v, oaccA[dt], 0, 0, 0);
      oaccB[dt] = __builtin_amdgcn_mfma_f32_16x16x32_bf16(vf, frB.v, oaccB[dt], 0, 0, 0);
    }
    __builtin_amdgcn_s_setprio(0);

    // ---- all my LDS reads retired before anyone overwrites this buffer
    asm volatile("s_waitcnt lgkmcnt(0)" ::: "memory");
    __builtin_amdgcn_sched_barrier(0);
    __builtin_amdgcn_s_barrier();
  }

  // ---- epilogue: reduce denoms, write both q-tiles
  float ltA = lA;
  ltA += __shfl_xor(ltA, 16);
  ltA += __shfl_xor(ltA, 32);
  float invA = 1.0f / ltA;
  float ltB = lB;
  ltB += __shfl_xor(ltB, 16);
  ltB += __shfl_xor(ltB, 32);
  float invB = 1.0f / ltB;

  float* opA = out + ((size_t)(seq0 + qtA * 64 + qlocal) * HQ + h) * DH;
  float* opB = out + ((size_t)(seq0 + qtB * 64 + qlocal) * HQ + h) * DH;
#pragma unroll
  for (int dt = 0; dt < 8; ++dt) {
    f4 wa, wb;
    wa[0] = oaccA[dt][0] * invA; wa[1] = oaccA[dt][1] * invA;
    wa[2] = oaccA[dt][2] * invA; wa[3] = oaccA[dt][3] * invA;
    wb[0] = oaccB[dt][0] * invB; wb[1] = oaccB[dt][1] * invB;
    wb[2] = oaccB[dt][2] * invB; wb[3] = oaccB[dt][3] * invB;
    *(f4*)(opA + dt * 16 + quad * 4) = wa;
    *(f4*)(opB + dt * 16 + quad * 4) = wb;
  }
}

extern "C" void kernel_launch(void* const* d_in, const int* in_sizes, int n_in,
                              void* d_out, int out_size, void* d_ws, size_t ws_size,
                              hipStream_t stream) {
  const float* q = (const float*)d_in[0];
  const float* k = (const float*)d_in[1];
  const float* v = (const float*)d_in[2];
  float* out = (float*)d_out;

  short* kbt = (short*)d_ws;                       // 4 MB fragment-major K (logical keys)
  short* vbt = kbt + (size_t)16 * 16 * 8192;       // 4 MB fragment-major V^T (interleaved keys)

  prep_kernel<<<dim3(1024), 256, 0, stream>>>(k, v, kbt, vbt);
  fa_main<<<dim3(512), 256, 0, stream>>>(q, kbt, vbt, out);
}

// Round 7
// 125.231 us; speedup vs baseline: 1.7640x; 1.7640x over previous
//
#include <hip/hip_runtime.h>

typedef __attribute__((ext_vector_type(8))) short s8bf;    // 8 x bf16
typedef __attribute__((ext_vector_type(4))) float f4;
typedef __attribute__((ext_vector_type(2))) unsigned u2;
typedef __attribute__((ext_vector_type(4))) unsigned u4;

#define HQ 32
#define HK 8
#define DH 128

// single-instruction pack of 2 f32 -> 2 bf16 (RNE); no builtin on gfx950
static __device__ __forceinline__ unsigned cvtpk(float a, float b) {
  unsigned r;
  asm("v_cvt_pk_bf16_f32 %0, %1, %2" : "=v"(r) : "v"(a), "v"(b));
  return r;
}
union frag_u { s8bf v; unsigned u[4]; };

// async global->LDS, 16B per lane; LDS dest is wave-uniform base + lane*16.
static __device__ __forceinline__ void gload_lds16(const short* g, short* l) {
  __builtin_amdgcn_global_load_lds(
      (const __attribute__((address_space(1))) void*)g,
      (__attribute__((address_space(3))) void*)l, 16, 0, 0);
}

// Counted wait + scheduler fence (rule #18).
#define WAIT_VM(N)                                         \
  do {                                                     \
    asm volatile("s_waitcnt vmcnt(" #N ")" ::: "memory");  \
    __builtin_amdgcn_sched_barrier(0);                     \
  } while (0)

// K stored in LOGICAL key order. V stored with the key interleave that makes
// the S^T accumulator registers directly the PV B-fragment.

// ---------------- prepass ----------------
// blocks 0..511  : K -> bf16 frag-major [bg][kt64][f=ct*4+dk][lane]
// blocks 512..1023: V half-tiles (32 keys) -> frag-major via LDS transpose
__global__ void prep_kernel(const float* __restrict__ kg, const float* __restrict__ vg,
                            short* __restrict__ kbt, short* __restrict__ vbt) {
  const int blk = blockIdx.x;
  if (blk < 512) {
    const int gid = blk * 256 + threadIdx.x;
#pragma unroll
    for (int i = 0; i < 2; ++i) {
      int c = gid + i * 131072;
      int l16 = c & 15, quad = (c >> 4) & 3;
      int f = (c >> 6) & 15;
      int kt = (c >> 10) & 15;
      int bg = c >> 14;
      int b = bg >> 3, g = bg & 7;
      int key = kt * 64 + (f >> 2) * 16 + l16;
      int d0 = (f & 3) * 32 + quad * 8;
      const float* src = kg + (((size_t)(b * 1024 + key) * HK + g) * DH + d0);
      f4 a = *(const f4*)src, cc = *(const f4*)(src + 4);
      u4 w;
      w[0] = cvtpk(a[0], a[1]);   w[1] = cvtpk(a[2], a[3]);
      w[2] = cvtpk(cc[0], cc[1]); w[3] = cvtpk(cc[2], cc[3]);
      *(u4*)(kbt + (size_t)c * 8) = w;
    }
  } else {
    // V: one (bg,kt,half) 32x128 half-tile per block
    __shared__ short T[32 * 130];
    const int t = blk - 512;               // 0..511
    const int half = t & 1, tile = t >> 1; // half = ks
    const int bg = tile >> 4, kt = tile & 15;
    const int b = bg >> 3, g = bg & 7;
#pragma unroll
    for (int i = 0; i < 4; ++i) {
      int e = threadIdx.x * 4 + i * 1024;  // 32 key x 128 d
      int key = e >> 7, d = e & 127;
      f4 x = *(const f4*)(vg + (((size_t)(b * 1024 + kt * 64 + half * 32 + key) * HK + g) * DH + d));
      u2 w; w[0] = cvtpk(x[0], x[1]); w[1] = cvtpk(x[2], x[3]);
      *(u2*)&T[key * 130 + d] = w;
    }
    __syncthreads();
    short* dst = vbt + (size_t)(bg * 16 + kt) * 8192;
#pragma unroll
    for (int i = 0; i < 2; ++i) {
      int c = threadIdx.x + i * 256;       // 512 cells: frags f = dt*2+half
      int lane = c & 63, dt = c >> 6;
      int fidx = dt * 2 + half;
      int l16 = lane & 15, quad = (lane >> 4) & 3;
      int d = dt * 16 + l16;
      int k0 = quad * 4;                   // local keys for j=0..3
      int k1 = k0 + 16;                    // local keys for j=4..7
      u4 w;
      w[0] = (unsigned)(unsigned short)T[(k0 + 0) * 130 + d] |
             ((unsigned)(unsigned short)T[(k0 + 1) * 130 + d] << 16);
      w[1] = (unsigned)(unsigned short)T[(k0 + 2) * 130 + d] |
             ((unsigned)(unsigned short)T[(k0 + 3) * 130 + d] << 16);
      w[2] = (unsigned)(unsigned short)T[(k1 + 0) * 130 + d] |
             ((unsigned)(unsigned short)T[(k1 + 1) * 130 + d] << 16);
      w[3] = (unsigned)(unsigned short)T[(k1 + 2) * 130 + d] |
             ((unsigned)(unsigned short)T[(k1 + 3) * 130 + d] << 16);
      *(u4*)(dst + (size_t)(fidx * 64 + lane) * 8) = w;
    }
  }
}

// ---------------- main: single q-tile, 32-key KV tiles, 32KB LDS, 4 blocks/CU ----------------
// R4's register footprint (~88, fits the 128 cap) with 2x the co-resident waves.
__launch_bounds__(256, 4)
__global__ void fa_main(const float* __restrict__ qg, const short* __restrict__ kbt,
                        const short* __restrict__ vbt, float* __restrict__ out) {
  const int id  = blockIdx.x;            // 0..1023; id&7 -> XCD-aligned kv-head
  const int g   = id & 7;
  const int s   = id >> 3;               // 0..127
  const int qt  = 15 - (s >> 3);         // longest blocks dispatched first
  const int rem = s & 7;
  const int b   = rem >> 2;
  const int h   = g * 4 + (rem & 3);
  const int bg  = b * 8 + g;
  const int kmax = 2 * qt + 1;           // last 32-key tile (B diagonal)

  const int tid  = threadIdx.x;
  const int wave = tid >> 6, lane = tid & 63;
  const int l16  = lane & 15, quad = lane >> 4;
  const int qlocal = wave * 16 + l16;
  const int seq0 = b * 1024;

  // [buf][ K frags: 0..4095 shorts | V frags: 4096..8191 ]  = 32 KB total
  __shared__ short smem[2][8192];

  // ---- Q fragment, softmax scale folded in (exp2 domain)
  const float qmul = 0.08838834764831845f * 1.4426950408889634f;
  const float* qp = qg + ((size_t)(seq0 + qt * 64 + qlocal) * HQ + h) * DH;
  s8bf qf[4];
#pragma unroll
  for (int dk = 0; dk < 4; ++dk) {
    const float* p = qp + dk * 32 + quad * 8;
    f4 a = *(const f4*)p, c = *(const f4*)(p + 4);
    frag_u t;
    t.u[0] = cvtpk(a[0] * qmul, a[1] * qmul);
    t.u[1] = cvtpk(a[2] * qmul, a[3] * qmul);
    t.u[2] = cvtpk(c[0] * qmul, c[1] * qmul);
    t.u[3] = cvtpk(c[2] * qmul, c[3] * qmul);
    qf[dk] = t.v;
  }

  float l_ = 0.0f;                        // per-lane partial denom (reduced at epilogue)
  f4 oacc[8];
#pragma unroll
  for (int dt = 0; dt < 8; ++dt) oacc[dt] = (f4)(0.0f);

  // K 32-tile j: kbt tile (j>>1), shorts offset (j&1)*4096, 8 contiguous 1KB frags.
  // V 32-tile j: vbt tile (j>>1), frag dt at shorts offset (j&1)*512 + dt*1024.
  const short* ktile = kbt + (size_t)bg * 16 * 8192;
  const short* vtile = vbt + (size_t)bg * 16 * 8192;

  // ---- pin Q loads above the counted-vmcnt stream
  __builtin_amdgcn_sched_barrier(0);

  // ---- staging: 16 frags (8 K + 8 V) of 1KB, 4 per wave
#define STAGE_TILE(J, BUF)                                                             \
  do {                                                                                 \
    const short* kb32 = ktile + (size_t)((J) >> 1) * 8192 + ((J) & 1) * 4096;          \
    const short* vb32 = vtile + (size_t)((J) >> 1) * 8192 + ((J) & 1) * 512;           \
    _Pragma("unroll")                                                                  \
    for (int i = 0; i < 4; ++i) {                                                      \
      int fidx = wave * 4 + i;                                                         \
      if (fidx < 8) {                                                                  \
        gload_lds16(kb32 + (size_t)(fidx * 64 + lane) * 8, &smem[BUF][fidx * 512]);    \
      } else {                                                                         \
        gload_lds16(vb32 + (size_t)((fidx - 8) * 128 + lane) * 8,                      \
                    &smem[BUF][4096 + (fidx - 8) * 512]);                              \
      }                                                                                \
    }                                                                                  \
  } while (0)

  // ---- preloop: stage tile 0 into buf 0
  STAGE_TILE(0, 0);

  for (int kt = 0; kt <= kmax; ++kt) {
    const int cur = kt & 1;

    if (kt < kmax) {
      STAGE_TILE(kt + 1, cur ^ 1);
      WAIT_VM(4);     // own tile-kt loads (older 4) landed; kt+1 stays in flight
    } else {
      WAIT_VM(0);     // last iteration: drain everything
    }
    __builtin_amdgcn_s_barrier();        // all waves' tile-kt loads landed
    __builtin_amdgcn_sched_barrier(0);

    const short* kb = &smem[cur][lane * 8];
    const short* vb = &smem[cur][4096 + lane * 8];

    // ---- S^T = K Q^T (2 key-subtiles x 4 dk)
    f4 sacc[2];
#pragma unroll
    for (int ct = 0; ct < 2; ++ct) sacc[ct] = (f4)(0.0f);
    __builtin_amdgcn_s_setprio(1);
#pragma unroll
    for (int dk = 0; dk < 4; ++dk)
#pragma unroll
      for (int ct = 0; ct < 2; ++ct) {
        s8bf kf = *(const s8bf*)&kb[(ct * 4 + dk) * 512];
        sacc[ct] = __builtin_amdgcn_mfma_f32_16x16x32_bf16(kf, qf[dk], sacc[ct], 0, 0, 0);
      }
    __builtin_amdgcn_s_setprio(0);

    // ---- causal mask: key_local > qlocal - (kt - 2qt)*32 -> -inf
    if (kt >= 2 * qt) {
      int thr = qlocal - (kt - 2 * qt) * 32;
#pragma unroll
      for (int ct = 0; ct < 2; ++ct)
#pragma unroll
        for (int i = 0; i < 4; ++i) {
          int key = ct * 16 + quad * 4 + i;
          if (key > thr) sacc[ct][i] = -1e30f;
        }
    }

    // ---- static-max softmax: p = exp2(min(s,30)); normalization in epilogue
    float rs = 0.0f;
    frag_u fr;
#pragma unroll
    for (int ct = 0; ct < 2; ++ct) {
      float p0 = exp2f(fminf(sacc[ct][0], 30.0f));
      float p1 = exp2f(fminf(sacc[ct][1], 30.0f));
      float p2 = exp2f(fminf(sacc[ct][2], 30.0f));
      float p3 = exp2f(fminf(sacc[ct][3], 30.0f));
      rs += (p0 + p1) + (p2 + p3);
      fr.u[ct * 2 + 0] = cvtpk(p0, p1);
      fr.u[ct * 2 + 1] = cvtpk(p2, p3);
    }
    l_ += rs;

    // ---- O^T += V^T P^T : P fragment is a register rename of the packed exp2s
    __builtin_amdgcn_s_setprio(1);
#pragma unroll
    for (int dt = 0; dt < 8; ++dt) {
      s8bf vf = *(const s8bf*)&vb[dt * 512];
      oacc[dt] = __builtin_amdgcn_mfma_f32_16x16x32_bf16(vf, fr.v, oacc[dt], 0, 0, 0);
    }
    __builtin_amdgcn_s_setprio(0);

    // ---- all my LDS reads retired before anyone overwrites this buffer
    asm volatile("s_waitcnt lgkmcnt(0)" ::: "memory");
    __builtin_amdgcn_sched_barrier(0);
    __builtin_amdgcn_s_barrier();
  }

  // ---- epilogue: reduce l_ over quads, lane holds O^T[d=dt*16+quad*4+i][q=l16]
  float lt = l_;
  lt += __shfl_xor(lt, 16);
  lt += __shfl_xor(lt, 32);
  float inv = 1.0f / lt;
  float* op = out + ((size_t)(seq0 + qt * 64 + qlocal) * HQ + h) * DH;
#pragma unroll
  for (int dt = 0; dt < 8; ++dt) {
    f4 w;
    w[0] = oacc[dt][0] * inv; w[1] = oacc[dt][1] * inv;
    w[2] = oacc[dt][2] * inv; w[3] = oacc[dt][3] * inv;
    *(f4*)(op + dt * 16 + quad * 4) = w;
  }
}

extern "C" void kernel_launch(void* const* d_in, const int* in_sizes, int n_in,
                              void* d_out, int out_size, void* d_ws, size_t ws_size,
                              hipStream_t stream) {
  const float* q = (const float*)d_in[0];
  const float* k = (const float*)d_in[1];
  const float* v = (const float*)d_in[2];
  float* out = (float*)d_out;

  short* kbt = (short*)d_ws;                       // 4 MB fragment-major K (logical keys)
  short* vbt = kbt + (size_t)16 * 16 * 8192;       // 4 MB fragment-major V^T (interleaved keys)

  prep_kernel<<<dim3(1024), 256, 0, stream>>>(k, v, kbt, vbt);
  fa_main<<<dim3(1024), 256, 0, stream>>>(q, kbt, vbt, out);
}